// Round 1
// baseline (659.216 us; speedup 1.0000x reference)
//
#include <hip/hip_runtime.h>
#include <math.h>

// Problem constants (fixed by the reference)
constexpr int B  = 2048;
constexpr int S  = 200;
constexpr int D  = 64;
constexpr int H  = 4;
constexpr int H1 = 64;
constexpr int H2 = 32;
constexpr int F  = 4 * D;   // 256

constexpr int ST = 100;     // s-rows per block (S/2)
constexpr int KP = 67;      // sK row pitch (odd -> conflict-free)
constexpr int W2P = 68;     // sW2T row pitch (16B-aligned rows)

// ---------------------------------------------------------------------------
// Kernel A: per (b, h, s-half) compute MLP scores for 100 key positions.
//   h1 = prelu( keys @ Weff + qt , a1 )
//   h2 = prelu( h1 @ W2 + b2 , a2 )
//   score = h2 . W3 + b3
// where Weff[d][k] = W1[h,d,k] + W1[h,192+d,k] + q_d * W1[h,128+d,k]
//       qt[k]      = b1[h,k] + sum_d q_d * (W1[h,64+d,k] - W1[h,192+d,k])
// ---------------------------------------------------------------------------
__global__ __launch_bounds__(256) void score_kernel(
    const float* __restrict__ query, const float* __restrict__ keys,
    const float* __restrict__ W1, const float* __restrict__ b1,
    const float* __restrict__ a1, const float* __restrict__ W2,
    const float* __restrict__ b2, const float* __restrict__ a2,
    const float* __restrict__ W3, const float* __restrict__ b3,
    float* __restrict__ scores)
{
    __shared__ float sK[ST * KP];      // keys tile [s][d], padded
    __shared__ float sWeff[D * H1];    // [d][k]
    __shared__ float sW2T[H2 * W2P];   // [m][k], padded
    __shared__ float sQt[H1];
    __shared__ float sW3[H2];
    __shared__ float sB2[H2];

    const int b    = blockIdx.x;
    const int h    = blockIdx.y;
    const int tile = blockIdx.z;      // 0 or 1
    const int s_off = tile * ST;
    const int t = threadIdx.x;

    // ---- stage keys tile (100x64 floats, coalesced float4 reads) ----
    {
        const float4* k4 = reinterpret_cast<const float4*>(
            keys + ((size_t)b * S + s_off) * D);
        for (int idx = t; idx < ST * D / 4; idx += 256) {
            float4 v = k4[idx];
            int sl = idx >> 4;            // 16 float4 per row
            int dc = (idx & 15) * 4;
            float* dst = &sK[sl * KP + dc];
            dst[0] = v.x; dst[1] = v.y; dst[2] = v.z; dst[3] = v.w;
        }
    }

    // ---- build Weff[d][k] ----
    {
        const int d  = t >> 2;
        const int kc = t & 3;
        const float qd = query[(size_t)b * D + d];
        const float* base = W1 + (size_t)h * F * H1;
        #pragma unroll
        for (int i = 0; i < 4; ++i) {
            const int k = kc * 16 + i * 4;
            float4 Ak = *reinterpret_cast<const float4*>(base + (size_t)d * H1 + k);
            float4 Ck = *reinterpret_cast<const float4*>(base + (size_t)(128 + d) * H1 + k);
            float4 Dk = *reinterpret_cast<const float4*>(base + (size_t)(192 + d) * H1 + k);
            float4 r;
            r.x = Ak.x + Dk.x + qd * Ck.x;
            r.y = Ak.y + Dk.y + qd * Ck.y;
            r.z = Ak.z + Dk.z + qd * Ck.z;
            r.w = Ak.w + Dk.w + qd * Ck.w;
            *reinterpret_cast<float4*>(&sWeff[d * H1 + k]) = r;
        }
    }

    // ---- qt[k] (64 threads) ----
    if (t < H1) {
        const int k = t;
        const float* base = W1 + (size_t)h * F * H1;
        float acc = b1[h * H1 + k];
        for (int d = 0; d < D; ++d) {
            const float qd = query[(size_t)b * D + d];
            acc += qd * (base[(size_t)(64 + d) * H1 + k] -
                         base[(size_t)(192 + d) * H1 + k]);
        }
        sQt[k] = acc;
    }

    // ---- stage W2 transposed [m][k] ----
    for (int idx = t; idx < H1 * H2; idx += 256) {
        int k = idx >> 5, m = idx & 31;
        sW2T[m * W2P + k] = W2[(size_t)h * H1 * H2 + idx];
    }
    if (t < H2) { sW3[t] = W3[h * H2 + t]; sB2[t] = b2[h * H2 + t]; }

    __syncthreads();

    const float a1v = a1[h], a2v = a2[h], b3v = b3[h];
    const int sg = t >> 2;    // 0..63, active < 50
    const int kc = t & 3;     // k-chunk of 16

    if (sg < 50) {
        const int s0 = sg;          // strided row pair: sg and sg+50
        const int s1 = sg + 50;
        const int kbase = kc * 16;

        // ---- layer 1: acc[2 rows][16 k] over d=0..63 ----
        float acc0[16] = {}, acc1[16] = {};
        #pragma unroll 2
        for (int d = 0; d < D; ++d) {
            const float x0 = sK[s0 * KP + d];
            const float x1 = sK[s1 * KP + d];
            const float4* wrow =
                reinterpret_cast<const float4*>(&sWeff[d * H1 + kbase]);
            #pragma unroll
            for (int i = 0; i < 4; ++i) {
                float4 w = wrow[i];
                acc0[4*i+0] += x0 * w.x; acc0[4*i+1] += x0 * w.y;
                acc0[4*i+2] += x0 * w.z; acc0[4*i+3] += x0 * w.w;
                acc1[4*i+0] += x1 * w.x; acc1[4*i+1] += x1 * w.y;
                acc1[4*i+2] += x1 * w.z; acc1[4*i+3] += x1 * w.w;
            }
        }

        // ---- + qt, PReLU ----
        float h10[16], h11[16];
        #pragma unroll
        for (int i = 0; i < 16; ++i) {
            const float q = sQt[kbase + i];
            float v0 = acc0[i] + q; h10[i] = v0 > 0.f ? v0 : a1v * v0;
            float v1 = acc1[i] + q; h11[i] = v1 > 0.f ? v1 : a1v * v1;
        }

        // ---- layer 2 partials over this thread's 16 k ----
        float h2p0[H2], h2p1[H2];
        #pragma unroll 4
        for (int m = 0; m < H2; ++m) {
            const float4* w2row =
                reinterpret_cast<const float4*>(&sW2T[m * W2P + kbase]);
            float d0 = 0.f, d1 = 0.f;
            #pragma unroll
            for (int i = 0; i < 4; ++i) {
                float4 w = w2row[i];
                d0 += h10[4*i+0]*w.x + h10[4*i+1]*w.y + h10[4*i+2]*w.z + h10[4*i+3]*w.w;
                d1 += h11[4*i+0]*w.x + h11[4*i+1]*w.y + h11[4*i+2]*w.z + h11[4*i+3]*w.w;
            }
            h2p0[m] = d0; h2p1[m] = d1;
        }

        // ---- butterfly reduce across the 4 k-chunk lanes ----
        #pragma unroll
        for (int m = 0; m < H2; ++m) {
            float v0 = h2p0[m], v1 = h2p1[m];
            v0 += __shfl_xor(v0, 1); v0 += __shfl_xor(v0, 2);
            v1 += __shfl_xor(v1, 1); v1 += __shfl_xor(v1, 2);
            h2p0[m] = v0; h2p1[m] = v1;
        }

        // ---- bias + PReLU + dot with W3 ----
        float sc0 = b3v, sc1 = b3v;
        #pragma unroll
        for (int m = 0; m < H2; ++m) {
            float v0 = h2p0[m] + sB2[m]; v0 = v0 > 0.f ? v0 : a2v * v0;
            float v1 = h2p1[m] + sB2[m]; v1 = v1 > 0.f ? v1 : a2v * v1;
            const float w3 = sW3[m];
            sc0 += v0 * w3; sc1 += v1 * w3;
        }

        if (kc == 0) {
            float* dst = scores + ((size_t)b * H + h) * S + s_off;
            dst[s0] = sc0;
            dst[s1] = sc1;
        }
    }
}

// ---------------------------------------------------------------------------
// Kernel B: per b — masked softmax per head (wave-per-head), weighted key
// sum, mean over heads, fused output projection.
// ---------------------------------------------------------------------------
__global__ __launch_bounds__(256) void attend_kernel(
    const float* __restrict__ keys, const int* __restrict__ mask,
    const float* __restrict__ scores, const float* __restrict__ Wo,
    const float* __restrict__ bo, float* __restrict__ out)
{
    __shared__ float4 sw4[S];          // weights per s, 4 heads packed
    __shared__ float  sred[4 * H * D]; // partial sums [sg][h][d]
    __shared__ float  scomb[D];

    const int b = blockIdx.x;
    const int t = threadIdx.x;
    const int wave = t >> 6;
    const int lane = t & 63;

    // ---- masked softmax, head = wave ----
    {
        const int hh = wave;
        const float* srow = scores + ((size_t)b * H + hh) * S;
        float v[4];
        int valid[4];
        float M = -INFINITY;
        #pragma unroll
        for (int c = 0; c < 4; ++c) {
            const int s = lane + 64 * c;
            const bool ok = (s < S);
            valid[c] = ok ? mask[(size_t)b * S + s] : 0;
            v[c] = (ok && valid[c]) ? srow[s] : -INFINITY;
            M = fmaxf(M, v[c]);
        }
        #pragma unroll
        for (int off = 32; off > 0; off >>= 1)
            M = fmaxf(M, __shfl_xor(M, off));
        float e[4];
        float Z = 0.f;
        #pragma unroll
        for (int c = 0; c < 4; ++c) {
            e[c] = valid[c] ? __expf(v[c] - M) : 0.f;
            Z += e[c];
        }
        #pragma unroll
        for (int off = 32; off > 0; off >>= 1)
            Z += __shfl_xor(Z, off);
        const float inv = (Z > 0.f) ? 1.f / Z : 0.f;
        #pragma unroll
        for (int c = 0; c < 4; ++c) {
            const int s = lane + 64 * c;
            if (s < S) reinterpret_cast<float*>(&sw4[s])[hh] = e[c] * inv;
        }
    }
    __syncthreads();

    // ---- weighted sums over keys (coalesced) ----
    const int d  = t & 63;
    const int sg = t >> 6;     // 4 groups of 50 s each
    float acc[H] = {0.f, 0.f, 0.f, 0.f};
    #pragma unroll 2
    for (int i = 0; i < 50; ++i) {
        const int s = sg * 50 + i;
        const float kv = keys[((size_t)b * S + s) * D + d];
        const float4 wv = sw4[s];
        acc[0] += wv.x * kv; acc[1] += wv.y * kv;
        acc[2] += wv.z * kv; acc[3] += wv.w * kv;
    }
    #pragma unroll
    for (int hh = 0; hh < H; ++hh)
        sred[(sg * H + hh) * D + d] = acc[hh];
    __syncthreads();

    // ---- mean over heads ----
    if (t < D) {
        float c = 0.f;
        #pragma unroll
        for (int i = 0; i < 4 * H; ++i) c += sred[i * D + t];
        scomb[t] = c * (1.0f / H);
    }
    __syncthreads();

    // ---- output projection ----
    if (t < D) {
        float o = bo[t];
        for (int dd = 0; dd < D; ++dd)
            o += scomb[dd] * Wo[dd * D + t];
        out[(size_t)b * D + t] = o;
    }
}

// ---------------------------------------------------------------------------
extern "C" void kernel_launch(void* const* d_in, const int* in_sizes, int n_in,
                              void* d_out, int out_size, void* d_ws, size_t ws_size,
                              hipStream_t stream) {
    const float* query = (const float*)d_in[0];
    const float* keys  = (const float*)d_in[1];
    const int*   mask  = (const int*)d_in[2];
    const float* W1 = (const float*)d_in[3];
    const float* b1 = (const float*)d_in[4];
    const float* a1 = (const float*)d_in[5];
    const float* W2 = (const float*)d_in[6];
    const float* b2 = (const float*)d_in[7];
    const float* a2 = (const float*)d_in[8];
    const float* W3 = (const float*)d_in[9];
    const float* b3 = (const float*)d_in[10];
    const float* Wo = (const float*)d_in[11];
    const float* bo = (const float*)d_in[12];

    float* out    = (float*)d_out;
    float* scores = (float*)d_ws;   // B*H*S floats = 6.55 MB

    dim3 gA(B, H, 2);
    score_kernel<<<gA, 256, 0, stream>>>(query, keys, W1, b1, a1,
                                         W2, b2, a2, W3, b3, scores);
    attend_kernel<<<dim3(B), 256, 0, stream>>>(keys, mask, scores, Wo, bo, out);
}

// Round 2
// 229.524 us; speedup vs baseline: 2.8721x; 2.8721x over previous
//
#include <hip/hip_runtime.h>
#include <math.h>

constexpr int B  = 2048;
constexpr int S  = 200;
constexpr int D  = 64;
constexpr int H  = 4;
constexpr int H1 = 64;
constexpr int H2 = 32;
constexpr int F  = 256;

constexpr int PK    = 72;    // bf16 LDS row pitch (multiple of 8, breaks bank-column alignment)
constexpr int SROWS = 208;   // 13 MFMA m-tiles

typedef short bf16x8 __attribute__((ext_vector_type(8)));
typedef float f32x4  __attribute__((ext_vector_type(4)));

__device__ __forceinline__ ushort f2bf(float x) {
    union { float f; unsigned u; } v; v.f = x;
    unsigned r = v.u + 0x7fffu + ((v.u >> 16) & 1u);   // RNE
    return (ushort)(r >> 16);
}
__device__ __forceinline__ float bf2f(ushort h) {
    union { unsigned u; float f; } v; v.u = ((unsigned)h) << 16; return v.f;
}

// One block per batch row b. 512 threads = 8 waves.
// Layer1 folded:  Weff[d][k] = W1[h,d,k] + W1[h,192+d,k] + q_d * W1[h,128+d,k]
//                 qt[k]      = b1[h,k] + sum_d q_d*(W1[h,64+d,k] - W1[h,192+d,k])
__global__ __launch_bounds__(512, 1) void fused_kernel(
    const float* __restrict__ query, const float* __restrict__ keys,
    const int* __restrict__ mask,
    const float* __restrict__ W1, const float* __restrict__ b1, const float* __restrict__ a1,
    const float* __restrict__ W2, const float* __restrict__ b2, const float* __restrict__ a2,
    const float* __restrict__ W3, const float* __restrict__ b3,
    const float* __restrict__ Wo, const float* __restrict__ bo,
    float* __restrict__ out)
{
    __shared__ ushort sKh[SROWS * PK];          // keys bf16 (hi only)
    __shared__ ushort sH1h[SROWS * PK];         // h1 hi
    __shared__ ushort sH1l[SROWS * PK];         // h1 lo
    __shared__ union UU {
        struct { ushort WTh[64 * PK], WTl[64 * PK], W2Th[32 * PK], W2Tl[32 * PK]; } w;
        struct { float4 sw4[SROWS]; float sred[8][4][64]; float po[8][64]; float comb[64]; } a;
    } U;
    __shared__ float sQ[64];
    __shared__ float sQt[4][64];
    __shared__ float sB2[4][32], sW3v[4][32];
    __shared__ float sScores[4][SROWS];

    const int b    = blockIdx.x;
    const int t    = threadIdx.x;
    const int lane = t & 63;
    const int wave = t >> 6;

    // ---------------- phase A: stage keys (bf16), query, small consts ----------------
    {
        const float4* k4 = (const float4*)(keys + (size_t)b * S * D);
        for (int idx = t; idx < S * D / 4; idx += 512) {
            float4 v = k4[idx];
            int s = idx >> 4, dc = (idx & 15) * 4;
            ushort4 hv; hv.x = f2bf(v.x); hv.y = f2bf(v.y); hv.z = f2bf(v.z); hv.w = f2bf(v.w);
            *(ushort4*)&sKh[s * PK + dc] = hv;
        }
        for (int idx = t; idx < 8 * PK; idx += 512) sKh[200 * PK + idx] = 0;  // pad rows
        if (t < 64) sQ[t] = query[(size_t)b * D + t];
        if (t < 128) { int hh = t >> 5, m = t & 31; sB2[hh][m] = b2[hh * 32 + m]; sW3v[hh][m] = W3[hh * 32 + m]; }
    }
    __syncthreads();

    // ---------------- qt[h][k] ----------------
    if (t < 256) {
        int hh = t >> 6, k = t & 63;
        const float* w1h = W1 + (size_t)hh * F * H1;
        float acc = b1[hh * 64 + k];
        #pragma unroll 8
        for (int d = 0; d < 64; ++d)
            acc += sQ[d] * (w1h[(64 + d) * 64 + k] - w1h[(192 + d) * 64 + k]);
        sQt[hh][k] = acc;
    }
    __syncthreads();

    // ---------------- per-head MLP ----------------
    for (int h = 0; h < H; ++h) {
        // build WeffT [k][d] and W2T [m][k], split hi/lo
        {
            const float* w1h = W1 + (size_t)h * F * H1;
            int k = t & 63, dg = t >> 6;
            #pragma unroll
            for (int j = 0; j < 8; ++j) {
                int d = dg * 8 + j;
                float w = w1h[d * 64 + k] + w1h[(192 + d) * 64 + k] + sQ[d] * w1h[(128 + d) * 64 + k];
                ushort hi = f2bf(w);
                U.w.WTh[k * PK + d] = hi;
                U.w.WTl[k * PK + d] = f2bf(w - bf2f(hi));
            }
            const float* w2h = W2 + (size_t)h * H1 * H2;
            int m = t & 31, kg = t >> 5;   // kg = 0..15
            #pragma unroll
            for (int j = 0; j < 4; ++j) {
                int k2 = kg * 4 + j;
                float w = w2h[k2 * 32 + m];
                ushort hi = f2bf(w);
                U.w.W2Th[m * PK + k2] = hi;
                U.w.W2Tl[m * PK + k2] = f2bf(w - bf2f(hi));
            }
        }
        __syncthreads();

        const float a1v = a1[h];

        // layer 1: h1[200][64] = prelu(keys @ Weff + qt)
        for (int mt = wave; mt < 13; mt += 8) {
            f32x4 acc[4] = { {0,0,0,0},{0,0,0,0},{0,0,0,0},{0,0,0,0} };
            #pragma unroll
            for (int kk = 0; kk < 2; ++kk) {
                const int koff = kk * 32 + (lane >> 4) * 8;
                bf16x8 a = *(const bf16x8*)&sKh[(mt * 16 + (lane & 15)) * PK + koff];
                #pragma unroll
                for (int nt = 0; nt < 4; ++nt) {
                    bf16x8 bh = *(const bf16x8*)&U.w.WTh[(nt * 16 + (lane & 15)) * PK + koff];
                    bf16x8 bl = *(const bf16x8*)&U.w.WTl[(nt * 16 + (lane & 15)) * PK + koff];
                    acc[nt] = __builtin_amdgcn_mfma_f32_16x16x32_bf16(a, bl, acc[nt], 0, 0, 0);
                    acc[nt] = __builtin_amdgcn_mfma_f32_16x16x32_bf16(a, bh, acc[nt], 0, 0, 0);
                }
            }
            #pragma unroll
            for (int nt = 0; nt < 4; ++nt) {
                const int col = nt * 16 + (lane & 15);
                const float qtv = sQt[h][col];
                #pragma unroll
                for (int i = 0; i < 4; ++i) {
                    int row = mt * 16 + (lane >> 4) * 4 + i;
                    float v = acc[nt][i] + qtv;
                    v = v > 0.f ? v : a1v * v;
                    ushort hi = f2bf(v);
                    sH1h[row * PK + col] = hi;
                    sH1l[row * PK + col] = f2bf(v - bf2f(hi));
                }
            }
        }
        __syncthreads();

        const float a2v = a2[h], b3v = b3[h];

        // layer 2 + 3: scores[s] = prelu(h1 @ W2 + b2) . W3 + b3
        for (int mt = wave; mt < 13; mt += 8) {
            f32x4 acc[2] = { {0,0,0,0},{0,0,0,0} };
            #pragma unroll
            for (int kk = 0; kk < 2; ++kk) {
                const int koff = kk * 32 + (lane >> 4) * 8;
                const int arow = (mt * 16 + (lane & 15)) * PK + koff;
                bf16x8 ah = *(const bf16x8*)&sH1h[arow];
                bf16x8 al = *(const bf16x8*)&sH1l[arow];
                #pragma unroll
                for (int nt = 0; nt < 2; ++nt) {
                    bf16x8 bh = *(const bf16x8*)&U.w.W2Th[(nt * 16 + (lane & 15)) * PK + koff];
                    bf16x8 bl = *(const bf16x8*)&U.w.W2Tl[(nt * 16 + (lane & 15)) * PK + koff];
                    acc[nt] = __builtin_amdgcn_mfma_f32_16x16x32_bf16(al, bh, acc[nt], 0, 0, 0);
                    acc[nt] = __builtin_amdgcn_mfma_f32_16x16x32_bf16(ah, bl, acc[nt], 0, 0, 0);
                    acc[nt] = __builtin_amdgcn_mfma_f32_16x16x32_bf16(ah, bh, acc[nt], 0, 0, 0);
                }
            }
            const int c0 = lane & 15, c1 = 16 + (lane & 15);
            const float w30 = sW3v[h][c0], w31 = sW3v[h][c1];
            const float bb0 = sB2[h][c0],  bb1 = sB2[h][c1];
            #pragma unroll
            for (int i = 0; i < 4; ++i) {
                float v0 = acc[0][i] + bb0; v0 = v0 > 0.f ? v0 : a2v * v0;
                float v1 = acc[1][i] + bb1; v1 = v1 > 0.f ? v1 : a2v * v1;
                float p = v0 * w30 + v1 * w31;
                p += __shfl_xor(p, 1); p += __shfl_xor(p, 2);
                p += __shfl_xor(p, 4); p += __shfl_xor(p, 8);
                if ((lane & 15) == 0) {
                    int row = mt * 16 + (lane >> 4) * 4 + i;
                    if (row < 200) sScores[h][row] = p + b3v;
                }
            }
        }
        __syncthreads();
    }

    // ---------------- attend: masked softmax (wave per head) ----------------
    if (wave < 4) {
        const int hh = wave;
        float v[4]; int valid[4];
        float M = -INFINITY;
        #pragma unroll
        for (int c = 0; c < 4; ++c) {
            int s = lane + 64 * c;
            bool ok = s < S;
            valid[c] = ok ? mask[(size_t)b * S + s] : 0;
            v[c] = (ok && valid[c]) ? sScores[hh][s] : -INFINITY;
            M = fmaxf(M, v[c]);
        }
        #pragma unroll
        for (int off = 32; off > 0; off >>= 1) M = fmaxf(M, __shfl_xor(M, off));
        float Z = 0.f, e[4];
        #pragma unroll
        for (int c = 0; c < 4; ++c) { e[c] = valid[c] ? __expf(v[c] - M) : 0.f; Z += e[c]; }
        #pragma unroll
        for (int off = 32; off > 0; off >>= 1) Z += __shfl_xor(Z, off);
        float inv = Z > 0.f ? 1.f / Z : 0.f;
        #pragma unroll
        for (int c = 0; c < 4; ++c) { int s = lane + 64 * c; if (s < S) ((float*)&U.a.sw4[s])[hh] = e[c] * inv; }
    }
    __syncthreads();

    // ---------------- weighted key sum ----------------
    {
        const int d = t & 63, sg = t >> 6;
        float a0 = 0.f, s1 = 0.f, s2 = 0.f, s3 = 0.f;
        #pragma unroll 5
        for (int i = 0; i < 25; ++i) {
            int s = sg * 25 + i;
            float kv = bf2f(sKh[s * PK + d]);
            float4 wv = U.a.sw4[s];
            a0 += wv.x * kv; s1 += wv.y * kv; s2 += wv.z * kv; s3 += wv.w * kv;
        }
        U.a.sred[sg][0][d] = a0; U.a.sred[sg][1][d] = s1;
        U.a.sred[sg][2][d] = s2; U.a.sred[sg][3][d] = s3;
    }
    __syncthreads();
    if (t < 64) {
        float c = 0.f;
        #pragma unroll
        for (int i = 0; i < 32; ++i) c += U.a.sred[i >> 2][i & 3][t];
        U.a.comb[t] = c * 0.25f;
    }
    __syncthreads();

    // ---------------- output projection ----------------
    {
        const int col = t & 63, g = t >> 6;
        float p = 0.f;
        #pragma unroll
        for (int j = 0; j < 8; ++j) { int dd = g * 8 + j; p += U.a.comb[dd] * Wo[dd * 64 + col]; }
        U.a.po[g][col] = p;
    }
    __syncthreads();
    if (t < 64) {
        float o = bo[t];
        #pragma unroll
        for (int g = 0; g < 8; ++g) o += U.a.po[g][t];
        out[(size_t)b * D + t] = o;
    }
}

extern "C" void kernel_launch(void* const* d_in, const int* in_sizes, int n_in,
                              void* d_out, int out_size, void* d_ws, size_t ws_size,
                              hipStream_t stream) {
    const float* query = (const float*)d_in[0];
    const float* keys  = (const float*)d_in[1];
    const int*   mask  = (const int*)d_in[2];
    const float* W1 = (const float*)d_in[3];
    const float* b1 = (const float*)d_in[4];
    const float* a1 = (const float*)d_in[5];
    const float* W2 = (const float*)d_in[6];
    const float* b2 = (const float*)d_in[7];
    const float* a2 = (const float*)d_in[8];
    const float* W3 = (const float*)d_in[9];
    const float* b3 = (const float*)d_in[10];
    const float* Wo = (const float*)d_in[11];
    const float* bo = (const float*)d_in[12];

    fused_kernel<<<dim3(B), 512, 0, stream>>>(query, keys, mask,
                                              W1, b1, a1, W2, b2, a2, W3, b3,
                                              Wo, bo, (float*)d_out);
}